// Round 11
// baseline (215.396 us; speedup 1.0000x reference)
//
#include <hip/hip_runtime.h>
#include <stdint.h>

// B=2, T=2048, D=1024, H=16, HS=64, DFF=4096
#define Bc   2
#define Tc   2048
#define Dc   1024
#define Hc   16
#define HSc  64
#define DFFc 4096
#define Mc   (Bc * Tc)   // 4096 rows

using f32x4 = __attribute__((ext_vector_type(4))) float;
using s16x8 = __attribute__((ext_vector_type(8))) short;

__device__ __forceinline__ ushort f2bf(float f) {
  union { float f; uint32_t u; } v; v.f = f;
  uint32_t r = (v.u + 0x7FFFu + ((v.u >> 16) & 1u)) >> 16;  // RNE
  return (ushort)r;
}
__device__ __forceinline__ float bf2f(ushort u) {
  union { uint32_t u; float f; } v; v.u = ((uint32_t)u) << 16;
  return v.f;
}
// pack two f32 -> 2x bf16 (RNE), lo = a, hi = b
__device__ __forceinline__ uint32_t cvtpk(float a, float b) {
  uint32_t r;
  asm volatile("v_cvt_pk_bf16_f32 %0, %1, %2" : "=v"(r) : "v"(a), "v"(b));
  return r;
}
__device__ __forceinline__ float wredsum(float v) {
#pragma unroll
  for (int o = 32; o > 0; o >>= 1) v += __shfl_down(v, o);
  return v;
}

// async global->LDS, 16B per lane; lds base must be wave-uniform
__device__ __forceinline__ void gload16(const ushort* g, ushort* l) {
  __builtin_amdgcn_global_load_lds(
      (const __attribute__((address_space(1))) void*)g,
      (__attribute__((address_space(3))) void*)l, 16, 0, 0);
}

// counted vmcnt wait (literal immediates only)
template <int N> __device__ __forceinline__ void vwait() {
  if constexpr (N == 0) asm volatile("s_waitcnt vmcnt(0)" ::: "memory");
  else if constexpr (N == 3) asm volatile("s_waitcnt vmcnt(3)" ::: "memory");
  else if constexpr (N == 4) asm volatile("s_waitcnt vmcnt(4)" ::: "memory");
  else if constexpr (N == 6) asm volatile("s_waitcnt vmcnt(6)" ::: "memory");
  else asm volatile("s_waitcnt vmcnt(8)" ::: "memory");
}

// Unified transpose+cast for ALL weights in one launch (12288 blocks)
__global__ __launch_bounds__(256) void tcast_all_kernel(
    const float* __restrict__ Wq, const float* __restrict__ Wk,
    const float* __restrict__ Wv, const float* __restrict__ Wo,
    const float* __restrict__ W1, const float* __restrict__ W2,
    ushort* __restrict__ wqkvt, ushort* __restrict__ wot,
    ushort* __restrict__ w1t, ushort* __restrict__ w2t) {
  __shared__ float t[32][33];
  const int id = blockIdx.x;
  const float* src; ushort* dst; int K, N, bx, by;
  if (id < 4096) {
    const int which = id >> 10, local = id & 1023;
    src = (which == 0) ? Wq : (which == 1) ? Wk : (which == 2) ? Wv : Wo;
    dst = (which == 3) ? wot : wqkvt + (size_t)which * 1024 * 1024;
    K = 1024; N = 1024; bx = local & 31; by = local >> 5;
  } else if (id < 8192) {
    const int local = id - 4096;
    src = W1; dst = w1t; K = 1024; N = 4096;
    bx = local & 127; by = local >> 7;
  } else {
    const int local = id - 8192;
    src = W2; dst = w2t; K = 4096; N = 1024;
    bx = local & 31; by = local >> 5;
  }
  const int tid = threadIdx.x;
  const int n0 = bx * 32, k0 = by * 32;
  const int r = tid >> 3, c4 = (tid & 7) * 4;
  const float4 v = *(const float4*)&src[(size_t)(k0 + r) * N + n0 + c4];
  t[r][c4] = v.x; t[r][c4 + 1] = v.y; t[r][c4 + 2] = v.z; t[r][c4 + 3] = v.w;
  __syncthreads();
  ushort4 o;
  o.x = f2bf(t[c4 + 0][r]); o.y = f2bf(t[c4 + 1][r]);
  o.z = f2bf(t[c4 + 2][r]); o.w = f2bf(t[c4 + 3][r]);
  *(ushort4*)&dst[(size_t)(n0 + r) * K + k0 + c4] = o;
}

// LayerNorm over D=1024, one block per row, fp32 in -> bf16 out
__global__ __launch_bounds__(256) void ln_kernel(const float* __restrict__ x,
                                                 const float* __restrict__ g,
                                                 const float* __restrict__ b,
                                                 ushort* __restrict__ out) {
  const int row = blockIdx.x;
  const int tid = threadIdx.x;
  const int lane = tid & 63, wave = tid >> 6;
  const float4 v = ((const float4*)(x + (size_t)row * Dc))[tid];
  float s  = v.x + v.y + v.z + v.w;
  float s2 = v.x * v.x + v.y * v.y + v.z * v.z + v.w * v.w;
  __shared__ float rs[4], rs2[4];
  s = wredsum(s); s2 = wredsum(s2);
  if (lane == 0) { rs[wave] = s; rs2[wave] = s2; }
  __syncthreads();
  const float S  = rs[0] + rs[1] + rs[2] + rs[3];
  const float S2 = rs2[0] + rs2[1] + rs2[2] + rs2[3];
  const float mu = S * (1.f / (float)Dc);
  const float rstd = rsqrtf(S2 * (1.f / (float)Dc) - mu * mu + 1e-5f);
  const float4 gv = ((const float4*)g)[tid];
  const float4 bv = ((const float4*)b)[tid];
  ushort4 o;
  o.x = f2bf((v.x - mu) * rstd * gv.x + bv.x);
  o.y = f2bf((v.y - mu) * rstd * gv.y + bv.y);
  o.z = f2bf((v.z - mu) * rstd * gv.z + bv.z);
  o.w = f2bf((v.w - mu) * rstd * gv.w + bv.w);
  ((ushort4*)(out + (size_t)row * Dc))[tid] = o;
}

// GEMM v3 (2-barrier, 4 waves) — kept for Wo. BMx128 tile, BK=64.
template <int BM, int NSPLIT, int OUT_BF16, int RELU, int BIAS, int RES, int QKVSPLIT>
__global__ __launch_bounds__(256) void gemm3_kernel(
    const ushort* __restrict__ A, const ushort* __restrict__ Bt,
    const float* __restrict__ bias, const float* __restrict__ res,
    void* __restrict__ C0, void* __restrict__ C1, void* __restrict__ C2,
    int M, int N, int K) {
  constexpr int MF = BM / 32;
  __shared__ __align__(16) ushort As[BM * 64];
  __shared__ __align__(16) ushort Bs[128 * 64];
  const int tid = threadIdx.x;
  const int lane = tid & 63, w = tid >> 6;
  const int wm = w >> 1, wn = w & 1;
  const int row0 = blockIdx.x * BM, col0 = blockIdx.y * 128;
  const int fr = lane & 15, fg = lane >> 4;
  const int kbeg = (NSPLIT > 1) ? blockIdx.z * (K / NSPLIT) : 0;
  const int kend = (NSPLIT > 1) ? kbeg + K / NSPLIT : K;

  f32x4 acc[MF][4] = {};

  for (int k0 = kbeg; k0 < kend; k0 += 64) {
#pragma unroll
    for (int i = 0; i < BM * 8 / 256; i++) {
      const int c = i * 256 + tid;
      const int r = c >> 3, j = c & 7;
      gload16(A + (size_t)(row0 + r) * K + k0 + ((j ^ (r & 7)) << 3),
              As + (i * 256 + w * 64) * 8);
    }
#pragma unroll
    for (int i = 0; i < 4; i++) {
      const int c = i * 256 + tid;
      const int r = c >> 3, j = c & 7;
      gload16(Bt + (size_t)(col0 + r) * K + k0 + ((j ^ (r & 7)) << 3),
              Bs + (i * 256 + w * 64) * 8);
    }
    __syncthreads();

#pragma unroll
    for (int kk = 0; kk < 2; kk++) {
      const int js = ((kk * 4 + fg) ^ (fr & 7)) << 3;
      s16x8 af[MF], bfr[4];
#pragma unroll
      for (int m = 0; m < MF; m++)
        af[m] = *(const s16x8*)&As[(wm * (BM / 2) + m * 16 + fr) * 64 + js];
#pragma unroll
      for (int n = 0; n < 4; n++)
        bfr[n] = *(const s16x8*)&Bs[(wn * 64 + n * 16 + fr) * 64 + js];
#pragma unroll
      for (int m = 0; m < MF; m++)
#pragma unroll
        for (int n = 0; n < 4; n++)
          acc[m][n] = __builtin_amdgcn_mfma_f32_16x16x32_bf16(af[m], bfr[n], acc[m][n], 0, 0, 0);
    }
    __syncthreads();
  }

  void* Cb = C0;
  int cbase = col0;
  if (QKVSPLIT) {
    const int which = col0 >> 10;
    Cb = (which == 0) ? C0 : (which == 1) ? C1 : C2;
    cbase = col0 & 1023;
  }
  const int NW = QKVSPLIT ? 1024 : N;
#pragma unroll
  for (int m = 0; m < MF; m++) {
#pragma unroll
    for (int n = 0; n < 4; n++) {
#pragma unroll
      for (int i = 0; i < 4; i++) {
        const int r = row0 + wm * (BM / 2) + m * 16 + fg * 4 + i;
        const int c = cbase + wn * 64 + n * 16 + fr;
        float v = acc[m][n][i];
        if (BIAS) v += bias[col0 - cbase + c];
        if (RELU) v = fmaxf(v, 0.f);
        if (RES)  v += res[(size_t)r * NW + c];
        if (OUT_BF16) ((ushort*)Cb)[(size_t)r * NW + c] = f2bf(v);
        else          ((float*)Cb)[(size_t)r * NW + c] = v;
      }
    }
  }
}

// GEMM v5 (round-9 proven, race-free): fine-phase ring. BN=256, 8 waves.
// LDS = 4-slot ring of BK=32 subtiles. Per subtile: NPH phases of
// {ds_read frags | stage gloads of subtile s+3 | s_barrier | setprio 16 MFMA |
// counted vmcnt gate | s_barrier}. Epilogue: LDS-packed full-line stores
// (wave-private region; eliminates write-allocate partial-line traffic).
template <int BM, int NSPLIT, int OUT_BF16, int RELU, int BIAS, int RES, int QKVSPLIT>
__global__ __launch_bounds__(512, 2) void gemm8_kernel(
    const ushort* __restrict__ A, const ushort* __restrict__ Bt,
    const float* __restrict__ bias, const float* __restrict__ res,
    void* __restrict__ C0, void* __restrict__ C1, void* __restrict__ C2,
    int M, int N, int K) {
  constexpr int WR = BM / 2;             // wave rows (128 / 64)
  constexpr int FI = WR / 16;            // A frags per wave (8 / 4)
  constexpr int NPH = FI / 4;            // phases per subtile (2 / 1)
  constexpr int APASS = BM / 128;        // A gload passes (2 / 1)
  constexpr int LPS = APASS + 2;         // loads/thread per subtile (4 / 3)
  constexpr int SLOT = (BM + 256) * 32;  // ushorts per ring slot
  __shared__ __align__(16) ushort lds[4 * SLOT];

  const int tid = threadIdx.x;
  const int lane = tid & 63, w = tid >> 6;
  const int wm = w >> 2, wn = w & 3;
  const int fr = lane & 15, fg = lane >> 4;
  const int row0 = blockIdx.x * BM, col0 = blockIdx.y * 256;
  const int kbeg = (NSPLIT > 1) ? blockIdx.z * (K / NSPLIT) : 0;
  const int nt = (K / NSPLIT) / 32;

  const int scc = tid & 3;   // staging chunk col
  const int sr0 = tid >> 2;  // staging row within a 128-row pass

  f32x4 acc[FI][4] = {};

  auto STAGE_A = [&](int t) {
    const int k0 = kbeg + t * 32;
    ushort* base = lds + (size_t)(t & 3) * SLOT;
#pragma unroll
    for (int i = 0; i < APASS; ++i) {
      const int r = i * 128 + sr0;
      const int j = scc ^ ((r >> 1) & 3);
      gload16(A + (size_t)(row0 + r) * K + k0 + j * 8,
              base + (i * 512 + w * 64) * 8);
    }
  };
  auto STAGE_B = [&](int t) {
    const int k0 = kbeg + t * 32;
    ushort* base = lds + (size_t)(t & 3) * SLOT + BM * 32;
#pragma unroll
    for (int i = 0; i < 2; ++i) {
      const int r = i * 128 + sr0;
      const int j = scc ^ ((r >> 1) & 3);
      gload16(Bt + (size_t)(col0 + r) * K + k0 + j * 8,
              base + (i * 512 + w * 64) * 8);
    }
  };

  // prologue: 3 subtiles in flight, wait for the first (own loads), rendezvous
  STAGE_A(0); STAGE_B(0);
  STAGE_A(1); STAGE_B(1);
  STAGE_A(2); STAGE_B(2);
  vwait<2 * LPS>();
  __builtin_amdgcn_sched_barrier(0);
  __builtin_amdgcn_s_barrier();
  __builtin_amdgcn_sched_barrier(0);

  for (int s = 0; s < nt; ++s) {
    const ushort* sb = lds + (size_t)(s & 3) * SLOT;
    s16x8 bf[4];  // B-frags held across phases
#pragma unroll
    for (int ni = 0; ni < 4; ++ni) {
      const int rb = wn * 64 + ni * 16 + fr;
      const int ch = fg ^ ((rb >> 1) & 3);
      bf[ni] = *(const s16x8*)&sb[BM * 32 + rb * 32 + ch * 8];
    }
#pragma unroll
    for (int mh = 0; mh < NPH; ++mh) {
      s16x8 af[4];
#pragma unroll
      for (int mi = 0; mi < 4; ++mi) {
        const int ra = wm * WR + mh * 64 + mi * 16 + fr;
        const int ch = fg ^ ((ra >> 1) & 3);
        af[mi] = *(const s16x8*)&sb[ra * 32 + ch * 8];
      }
      if (s + 3 < nt) {
        if constexpr (NPH == 2) {
          if (mh == 0) STAGE_A(s + 3); else STAGE_B(s + 3);
        } else {
          STAGE_A(s + 3); STAGE_B(s + 3);
        }
      }
      __builtin_amdgcn_sched_barrier(0);
      __builtin_amdgcn_s_barrier();
      __builtin_amdgcn_sched_barrier(0);
      __builtin_amdgcn_s_setprio(1);
#pragma unroll
      for (int mi = 0; mi < 4; ++mi)
#pragma unroll
        for (int ni = 0; ni < 4; ++ni)
          acc[mh * 4 + mi][ni] = __builtin_amdgcn_mfma_f32_16x16x32_bf16(
              af[mi], bf[ni], acc[mh * 4 + mi][ni], 0, 0, 0);
      __builtin_amdgcn_s_setprio(0);
      __builtin_amdgcn_sched_barrier(0);
      if (mh == NPH - 1) {  // gate subtile s+1 BEFORE the collective barrier
        const int rem = nt - 2 - s;
        if (rem >= 2) vwait<2 * LPS>();
        else if (rem == 1) vwait<LPS>();
        else if (rem == 0) vwait<0>();
      }
      __builtin_amdgcn_s_barrier();
      __builtin_amdgcn_sched_barrier(0);
    }
  }

  // ---- epilogue: LDS-pack wave tile, then 128B-line coalesced stores ----
  // C/D layout: col = lane&15, row = (lane>>4)*4 + reg
  __syncthreads();  // all ring-slot reads complete before repurposing LDS
  if constexpr (NSPLIT > 1 || OUT_BF16) {
    ushort* wst = lds + w * (WR * 64);  // wave-private region
#pragma unroll
    for (int mi = 0; mi < FI; ++mi) {
#pragma unroll
      for (int ni = 0; ni < 4; ++ni) {
#pragma unroll
        for (int i = 0; i < 4; ++i) {
          float v = acc[mi][ni][i];
          if (NSPLIT == 1) {
            if (BIAS) v += bias[col0 + wn * 64 + ni * 16 + fr];
            if (RELU) v = fmaxf(v, 0.f);
          }
          wst[(mi * 16 + fg * 4 + i) * 64 + ni * 16 + fr] = f2bf(v);
        }
      }
    }
    const int rr = lane >> 3, cc = (lane & 7) * 8;
    if constexpr (NSPLIT > 1) {
      ushort* P = (ushort*)C0 + (size_t)blockIdx.z * M * N;  // bf16 partials
#pragma unroll
      for (int it = 0; it < WR / 8; ++it) {
        const int r = it * 8 + rr;
        *(uint4*)&P[(size_t)(row0 + wm * WR + r) * N + col0 + wn * 64 + cc] =
            *(const uint4*)&wst[r * 64 + cc];
      }
    } else {
      void* Cb = C0;
      int cbase = col0;
      if (QKVSPLIT) {
        const int which = col0 >> 10;
        Cb = (which == 0) ? C0 : (which == 1) ? C1 : C2;
        cbase = col0 & 1023;
      }
      const int NW = QKVSPLIT ? 1024 : N;
#pragma unroll
      for (int it = 0; it < WR / 8; ++it) {
        const int r = it * 8 + rr;
        *(uint4*)&((ushort*)Cb)[(size_t)(row0 + wm * WR + r) * NW + cbase + wn * 64 + cc] =
            *(const uint4*)&wst[r * 64 + cc];
      }
    }
  } else {
    // fp32 direct path (unused by current launch set)
#pragma unroll
    for (int mi = 0; mi < FI; ++mi)
#pragma unroll
      for (int ni = 0; ni < 4; ++ni)
#pragma unroll
        for (int i = 0; i < 4; ++i) {
          const int r = row0 + wm * WR + mi * 16 + fg * 4 + i;
          const int c = col0 + wn * 64 + ni * 16 + fr;
          float v = acc[mi][ni][i];
          if (BIAS) v += bias[c];
          if (RELU) v = fmaxf(v, 0.f);
          if (RES)  v += res[(size_t)r * N + c];
          ((float*)C0)[(size_t)r * N + c] = v;
        }
  }
}

// out = p0 + p1 (bf16 partials) + bias[col] + res (fp32), N=1024
__global__ __launch_bounds__(256) void sum2b_kernel(const ushort* __restrict__ p,
                                                    const float* __restrict__ bias,
                                                    const float* __restrict__ res,
                                                    float* __restrict__ out) {
  const size_t i = ((size_t)blockIdx.x * 256 + threadIdx.x) * 4;
  const size_t MN = (size_t)Mc * Dc;
  const ushort4 a = *(const ushort4*)(p + i);
  const ushort4 b = *(const ushort4*)(p + MN + i);
  const float4 r = *(const float4*)(res + i);
  const float4 bs = *(const float4*)(bias + (i & 1023));
  float4 o;
  o.x = bf2f(a.x) + bf2f(b.x) + bs.x + r.x;
  o.y = bf2f(a.y) + bf2f(b.y) + bs.y + r.y;
  o.z = bf2f(a.z) + bf2f(b.z) + bs.z + r.z;
  o.w = bf2f(a.w) + bf2f(b.w) + bs.w + r.w;
  *(float4*)(out + i) = o;
}

// Flash attention v3 (causal): 8 waves, QBLK=128, KVBLK=64, split-KV x2.
__global__ __launch_bounds__(512) void fattn3_kernel(const ushort* __restrict__ Q,
                                                     const ushort* __restrict__ K,
                                                     const ushort* __restrict__ V,
                                                     float* __restrict__ pacc,
                                                     float* __restrict__ pl) {
  __shared__ __align__(16) ushort Kl[2][64][72];
  __shared__ __align__(16) ushort Vt[2][64][72];
  __shared__ __align__(16) uint32_t Pu[8][512];

  const int tid = threadIdx.x;
  const int lane = tid & 63, w = tid >> 6;
  const int fr = lane & 15, fg = lane >> 4;

  const int bh   = blockIdx.x & 31;
  const int rest = blockIdx.x >> 5;
  const int qb   = 15 - (rest >> 1);
  const int z    = rest & 1;
  const int h = bh & 15, b = bh >> 4;
  const int q0 = qb * 128;
  const size_t hbase = (size_t)b * Tc * Dc + (size_t)h * HSc;

  s16x8 qf0, qf1;
  {
    const ushort* qp = Q + hbase + (size_t)(q0 + w * 16 + fr) * Dc + fg * 8;
    qf0 = *(const s16x8*)(qp);
    qf1 = *(const s16x8*)(qp + 32);
  }

  const int kkey = tid >> 3, kd8 = (tid & 7) * 8;
  const int vkey = tid & 63, vd8 = (tid >> 6) * 8;

  const int t0 = z * (qb + 1), t1 = (z + 1) * (qb + 1);
  uint4 kreg = *(const uint4*)(K + hbase + (size_t)(t0 * 64 + kkey) * Dc + kd8);
  uint4 vreg = *(const uint4*)(V + hbase + (size_t)(t0 * 64 + vkey) * Dc + vd8);

  f32x4 acc[4] = {};
  float ps = 0.f;
  const float Cs = 0.18033688f;  // log2(e)/8 (folds the 1/sqrt(64) scale)

  for (int kt = t0; kt < t1; kt++) {
    const int cur = (kt - t0) & 1;
    *(uint4*)&Kl[cur][kkey][kd8] = kreg;
    {
      union { uint4 v; ushort u[8]; } t; t.v = vreg;
#pragma unroll
      for (int j = 0; j < 8; j++) Vt[cur][vd8 + j][vkey] = t.u[j];
    }
    if (kt + 1 < t1) {
      kreg = *(const uint4*)(K + hbase + (size_t)((kt + 1) * 64 + kkey) * Dc + kd8);
      vreg = *(const uint4*)(V + hbase + (size_t)((kt + 1) * 64 + vkey) * Dc + vd8);
    }
    __syncthreads();

    const bool skip = (kt * 64 > q0 + w * 16 + 15);
    if (!skip) {
      f32x4 s[4] = {};
      __builtin_amdgcn_s_setprio(1);
#pragma unroll
      for (int kf = 0; kf < 4; kf++) {
        const s16x8 k0 = *(const s16x8*)&Kl[cur][kf * 16 + fr][fg * 8];
        const s16x8 k1 = *(const s16x8*)&Kl[cur][kf * 16 + fr][32 + fg * 8];
        s[kf] = __builtin_amdgcn_mfma_f32_16x16x32_bf16(k0, qf0, s[kf], 0, 0, 0);
        s[kf] = __builtin_amdgcn_mfma_f32_16x16x32_bf16(k1, qf1, s[kf], 0, 0, 0);
      }
      __builtin_amdgcn_s_setprio(0);

      const bool diag = (kt * 64 + 63 > q0 + w * 16);
      const int qg = q0 + w * 16 + fr;
#pragma unroll
      for (int kf = 0; kf < 4; kf++) {
        float p[4];
#pragma unroll
        for (int i = 0; i < 4; i++) {
          p[i] = exp2f(s[kf][i] * Cs);
          if (diag) {
            const int kg = kt * 64 + kf * 16 + fg * 4 + i;
            if (kg > qg) p[i] = 0.f;
          }
          ps += p[i];
        }
        uint2 pk;
        pk.x = cvtpk(p[0], p[1]);
        pk.y = cvtpk(p[2], p[3]);
        *(uint2*)&Pu[w][(2 * kf + (fg >> 1)) * 64 + fr * 4 + (fg & 1) * 2] = pk;
      }

      const s16x8 pa0 = *(const s16x8*)&Pu[w][fg * 64 + fr * 4];
      const s16x8 pa1 = *(const s16x8*)&Pu[w][(4 + fg) * 64 + fr * 4];
      __builtin_amdgcn_s_setprio(1);
#pragma unroll
      for (int df = 0; df < 4; df++) {
        const s16x8 v0 = *(const s16x8*)&Vt[cur][df * 16 + fr][fg * 8];
        const s16x8 v1 = *(const s16x8*)&Vt[cur][df * 16 + fr][32 + fg * 8];
        acc[df] = __builtin_amdgcn_mfma_f32_16x16x32_bf16(pa0, v0, acc[df], 0, 0, 0);
        acc[df] = __builtin_amdgcn_mfma_f32_16x16x32_bf16(pa1, v1, acc[df], 0, 0, 0);
      }
      __builtin_amdgcn_s_setprio(0);
    }
  }

  ps += __shfl_xor(ps, 16);
  ps += __shfl_xor(ps, 32);
  if (lane < 16)
    pl[(size_t)z * (32 * 2048) + (size_t)bh * 2048 + q0 + w * 16 + lane] = ps;

  float* pa = pacc + (size_t)z * (32ull * 2048 * 64) + (size_t)bh * 2048 * 64;
#pragma unroll
  for (int i = 0; i < 4; i++) {
    const int qr = q0 + w * 16 + fg * 4 + i;
#pragma unroll
    for (int df = 0; df < 4; df++)
      pa[(size_t)qr * 64 + df * 16 + fr] = acc[df][i];
  }
}

// merge split-KV partials: O[b,t,h*64+d] = bf16((accA+accB)/(lA+lB))
__global__ __launch_bounds__(256) void amerge_kernel(const float* __restrict__ pacc,
                                                     const float* __restrict__ pl,
                                                     ushort* __restrict__ O) {
  const int g = blockIdx.x * 256 + threadIdx.x;
  const int d4 = g & 15;
  const int t  = (g >> 4) & 2047;
  const int bh = g >> 15;
  const int h = bh & 15, b = bh >> 4;
  const size_t base = ((size_t)bh * 2048 + t) * 64 + d4 * 4;
  const float4 a = *(const float4*)(pacc + base);
  const float4 c = *(const float4*)(pacc + 32ull * 2048 * 64 + base);
  const float inv = 1.f / (pl[(size_t)bh * 2048 + t] + pl[32 * 2048 + (size_t)bh * 2048 + t]);
  ushort4 o;
  o.x = f2bf((a.x + c.x) * inv);
  o.y = f2bf((a.y + c.y) * inv);
  o.z = f2bf((a.z + c.z) * inv);
  o.w = f2bf((a.w + c.w) * inv);
  *(ushort4*)&O[((size_t)(b * 2048 + t)) * 1024 + h * 64 + d4 * 4] = o;
}

extern "C" void kernel_launch(void* const* d_in, const int* in_sizes, int n_in,
                              void* d_out, int out_size, void* d_ws, size_t ws_size,
                              hipStream_t stream) {
  const float* x   = (const float*)d_in[0];
  const float* Wq  = (const float*)d_in[1];
  const float* Wk  = (const float*)d_in[2];
  const float* Wv  = (const float*)d_in[3];
  const float* Wo  = (const float*)d_in[4];
  const float* bo  = (const float*)d_in[5];
  const float* W1  = (const float*)d_in[6];
  const float* b1  = (const float*)d_in[7];
  const float* W2  = (const float*)d_in[8];
  const float* b2  = (const float*)d_in[9];
  const float* g1  = (const float*)d_in[10];
  const float* be1 = (const float*)d_in[11];
  const float* g2  = (const float*)d_in[12];
  const float* be2 = (const float*)d_in[13];

  char* ws = (char*)d_ws;
  const size_t MB = 1ull << 20;
  ushort* ln1   = (ushort*)(ws + 0 * MB);   // [M,D] bf16; reused as attn-out
  ushort* qb    = (ushort*)(ws + 8 * MB);   // [M,D] bf16; reused as ln2
  ushort* kb    = (ushort*)(ws + 16 * MB);  // [M,D] bf16
  ushort* vb    = (ushort*)(ws + 24 * MB);  // [M,D] bf16
  ushort* wqkvt = (ushort*)(ws + 32 * MB);  // [3072,1024] bf16
  ushort* wot   = (ushort*)(ws + 38 * MB);  // [1024,1024] bf16
  ushort* w1t   = (ushort*)(ws + 40 * MB);  // [4096,1024] bf16
  ushort* w2t   = (ushort*)(ws + 48 * MB);  // [1024,4096] bf16
  float*  x1    = (float*)(ws + 56 * MB);   // [M,D] f32 (post-attn residual)
  ushort* hb    = (ushort*)(ws + 72 * MB);  // [M,DFF] bf16 (ends at 104 MB)
  float*  pacc  = (float*)(ws + 56 * MB);   // attn partials 2x16MB (56..88)
  float*  plv   = (float*)(ws + 88 * MB);   // attn l partials 2x256KB
  ushort* fpart = (ushort*)(ws + 0 * MB);   // FFN2 bf16 partials: 2x8MB
                                            // (overlays ln1+qb, dead by then)

  tcast_all_kernel<<<12288, 256, 0, stream>>>(Wq, Wk, Wv, Wo, W1, W2,
                                              wqkvt, wot, w1t, w2t);

  ln_kernel<<<Mc, 256, 0, stream>>>(x, g1, be1, ln1);

  // fused QKV projection (ring BM=128): N=3072, split outputs, 384 blocks
  gemm8_kernel<128, 1, 1, 0, 0, 0, 1><<<dim3(32, 12), 512, 0, stream>>>(
      ln1, wqkvt, nullptr, nullptr, qb, kb, vb, Mc, 3072, Dc);

  // flash attention v3: split-KV partials, then linear merge into ln1
  fattn3_kernel<<<1024, 512, 0, stream>>>(qb, kb, vb, pacc, plv);
  amerge_kernel<<<4096, 256, 0, stream>>>(pacc, plv, ln1);

  // output projection + bias + residual(x) -> x1 (fp32)
  gemm3_kernel<64, 1, 0, 0, 1, 1, 0><<<dim3(64, 8), 256, 0, stream>>>(
      ln1, wot, bo, x, x1, nullptr, nullptr, Mc, Dc, Dc);

  ln_kernel<<<Mc, 256, 0, stream>>>(x1, g2, be2, qb);

  // FFN1 (ring BM=256): relu(ln2 @ W1 + b1) -> hb (bf16)
  gemm8_kernel<256, 1, 1, 1, 1, 0, 0><<<dim3(16, 16), 512, 0, stream>>>(
      qb, w1t, b1, nullptr, hb, nullptr, nullptr, Mc, DFFc, Dc);

  // FFN2 (ring BM=128, split-K x2, bf16 partials), then sum -> d_out
  gemm8_kernel<128, 2, 0, 0, 0, 0, 0><<<dim3(32, 4, 2), 512, 0, stream>>>(
      hb, w2t, nullptr, nullptr, fpart, nullptr, nullptr, Mc, Dc, DFFc);
  sum2b_kernel<<<4096, 256, 0, stream>>>(fpart, b2, x1, (float*)d_out);
}

// Round 12
// 214.429 us; speedup vs baseline: 1.0045x; 1.0045x over previous
//
#include <hip/hip_runtime.h>
#include <stdint.h>

// B=2, T=2048, D=1024, H=16, HS=64, DFF=4096
#define Bc   2
#define Tc   2048
#define Dc   1024
#define Hc   16
#define HSc  64
#define DFFc 4096
#define Mc   (Bc * Tc)   // 4096 rows

using f32x4 = __attribute__((ext_vector_type(4))) float;
using s16x8 = __attribute__((ext_vector_type(8))) short;

__device__ __forceinline__ ushort f2bf(float f) {
  union { float f; uint32_t u; } v; v.f = f;
  uint32_t r = (v.u + 0x7FFFu + ((v.u >> 16) & 1u)) >> 16;  // RNE
  return (ushort)r;
}
__device__ __forceinline__ float bf2f(ushort u) {
  union { uint32_t u; float f; } v; v.u = ((uint32_t)u) << 16;
  return v.f;
}
// pack two f32 -> 2x bf16 (RNE), lo = a, hi = b
__device__ __forceinline__ uint32_t cvtpk(float a, float b) {
  uint32_t r;
  asm volatile("v_cvt_pk_bf16_f32 %0, %1, %2" : "=v"(r) : "v"(a), "v"(b));
  return r;
}
__device__ __forceinline__ float wredsum(float v) {
#pragma unroll
  for (int o = 32; o > 0; o >>= 1) v += __shfl_down(v, o);
  return v;
}

// async global->LDS, 16B per lane; lds base must be wave-uniform
__device__ __forceinline__ void gload16(const ushort* g, ushort* l) {
  __builtin_amdgcn_global_load_lds(
      (const __attribute__((address_space(1))) void*)g,
      (__attribute__((address_space(3))) void*)l, 16, 0, 0);
}

// counted vmcnt wait (literal immediates only)
template <int N> __device__ __forceinline__ void vwait() {
  if constexpr (N == 0) asm volatile("s_waitcnt vmcnt(0)" ::: "memory");
  else if constexpr (N == 3) asm volatile("s_waitcnt vmcnt(3)" ::: "memory");
  else if constexpr (N == 4) asm volatile("s_waitcnt vmcnt(4)" ::: "memory");
  else if constexpr (N == 6) asm volatile("s_waitcnt vmcnt(6)" ::: "memory");
  else asm volatile("s_waitcnt vmcnt(8)" ::: "memory");
}

// Unified transpose+cast for ALL weights in one launch (12288 blocks)
__global__ __launch_bounds__(256) void tcast_all_kernel(
    const float* __restrict__ Wq, const float* __restrict__ Wk,
    const float* __restrict__ Wv, const float* __restrict__ Wo,
    const float* __restrict__ W1, const float* __restrict__ W2,
    ushort* __restrict__ wqkvt, ushort* __restrict__ wot,
    ushort* __restrict__ w1t, ushort* __restrict__ w2t) {
  __shared__ float t[32][33];
  const int id = blockIdx.x;
  const float* src; ushort* dst; int K, N, bx, by;
  if (id < 4096) {
    const int which = id >> 10, local = id & 1023;
    src = (which == 0) ? Wq : (which == 1) ? Wk : (which == 2) ? Wv : Wo;
    dst = (which == 3) ? wot : wqkvt + (size_t)which * 1024 * 1024;
    K = 1024; N = 1024; bx = local & 31; by = local >> 5;
  } else if (id < 8192) {
    const int local = id - 4096;
    src = W1; dst = w1t; K = 1024; N = 4096;
    bx = local & 127; by = local >> 7;
  } else {
    const int local = id - 8192;
    src = W2; dst = w2t; K = 4096; N = 1024;
    bx = local & 31; by = local >> 5;
  }
  const int tid = threadIdx.x;
  const int n0 = bx * 32, k0 = by * 32;
  const int r = tid >> 3, c4 = (tid & 7) * 4;
  const float4 v = *(const float4*)&src[(size_t)(k0 + r) * N + n0 + c4];
  t[r][c4] = v.x; t[r][c4 + 1] = v.y; t[r][c4 + 2] = v.z; t[r][c4 + 3] = v.w;
  __syncthreads();
  ushort4 o;
  o.x = f2bf(t[c4 + 0][r]); o.y = f2bf(t[c4 + 1][r]);
  o.z = f2bf(t[c4 + 2][r]); o.w = f2bf(t[c4 + 3][r]);
  *(ushort4*)&dst[(size_t)(n0 + r) * K + k0 + c4] = o;
}

// LayerNorm over D=1024, one block per row, fp32 in -> bf16 out
__global__ __launch_bounds__(256) void ln_kernel(const float* __restrict__ x,
                                                 const float* __restrict__ g,
                                                 const float* __restrict__ b,
                                                 ushort* __restrict__ out) {
  const int row = blockIdx.x;
  const int tid = threadIdx.x;
  const int lane = tid & 63, wave = tid >> 6;
  const float4 v = ((const float4*)(x + (size_t)row * Dc))[tid];
  float s  = v.x + v.y + v.z + v.w;
  float s2 = v.x * v.x + v.y * v.y + v.z * v.z + v.w * v.w;
  __shared__ float rs[4], rs2[4];
  s = wredsum(s); s2 = wredsum(s2);
  if (lane == 0) { rs[wave] = s; rs2[wave] = s2; }
  __syncthreads();
  const float S  = rs[0] + rs[1] + rs[2] + rs[3];
  const float S2 = rs2[0] + rs2[1] + rs2[2] + rs2[3];
  const float mu = S * (1.f / (float)Dc);
  const float rstd = rsqrtf(S2 * (1.f / (float)Dc) - mu * mu + 1e-5f);
  const float4 gv = ((const float4*)g)[tid];
  const float4 bv = ((const float4*)b)[tid];
  ushort4 o;
  o.x = f2bf((v.x - mu) * rstd * gv.x + bv.x);
  o.y = f2bf((v.y - mu) * rstd * gv.y + bv.y);
  o.z = f2bf((v.z - mu) * rstd * gv.z + bv.z);
  o.w = f2bf((v.w - mu) * rstd * gv.w + bv.w);
  ((ushort4*)(out + (size_t)row * Dc))[tid] = o;
}

// GEMM v3 (2-barrier, 4 waves) — kept for Wo. BMx128 tile, BK=64.
template <int BM, int NSPLIT, int OUT_BF16, int RELU, int BIAS, int RES, int QKVSPLIT>
__global__ __launch_bounds__(256) void gemm3_kernel(
    const ushort* __restrict__ A, const ushort* __restrict__ Bt,
    const float* __restrict__ bias, const float* __restrict__ res,
    void* __restrict__ C0, void* __restrict__ C1, void* __restrict__ C2,
    int M, int N, int K) {
  constexpr int MF = BM / 32;
  __shared__ __align__(16) ushort As[BM * 64];
  __shared__ __align__(16) ushort Bs[128 * 64];
  const int tid = threadIdx.x;
  const int lane = tid & 63, w = tid >> 6;
  const int wm = w >> 1, wn = w & 1;
  const int row0 = blockIdx.x * BM, col0 = blockIdx.y * 128;
  const int fr = lane & 15, fg = lane >> 4;
  const int kbeg = (NSPLIT > 1) ? blockIdx.z * (K / NSPLIT) : 0;
  const int kend = (NSPLIT > 1) ? kbeg + K / NSPLIT : K;

  f32x4 acc[MF][4] = {};

  for (int k0 = kbeg; k0 < kend; k0 += 64) {
#pragma unroll
    for (int i = 0; i < BM * 8 / 256; i++) {
      const int c = i * 256 + tid;
      const int r = c >> 3, j = c & 7;
      gload16(A + (size_t)(row0 + r) * K + k0 + ((j ^ (r & 7)) << 3),
              As + (i * 256 + w * 64) * 8);
    }
#pragma unroll
    for (int i = 0; i < 4; i++) {
      const int c = i * 256 + tid;
      const int r = c >> 3, j = c & 7;
      gload16(Bt + (size_t)(col0 + r) * K + k0 + ((j ^ (r & 7)) << 3),
              Bs + (i * 256 + w * 64) * 8);
    }
    __syncthreads();

#pragma unroll
    for (int kk = 0; kk < 2; kk++) {
      const int js = ((kk * 4 + fg) ^ (fr & 7)) << 3;
      s16x8 af[MF], bfr[4];
#pragma unroll
      for (int m = 0; m < MF; m++)
        af[m] = *(const s16x8*)&As[(wm * (BM / 2) + m * 16 + fr) * 64 + js];
#pragma unroll
      for (int n = 0; n < 4; n++)
        bfr[n] = *(const s16x8*)&Bs[(wn * 64 + n * 16 + fr) * 64 + js];
#pragma unroll
      for (int m = 0; m < MF; m++)
#pragma unroll
        for (int n = 0; n < 4; n++)
          acc[m][n] = __builtin_amdgcn_mfma_f32_16x16x32_bf16(af[m], bfr[n], acc[m][n], 0, 0, 0);
    }
    __syncthreads();
  }

  void* Cb = C0;
  int cbase = col0;
  if (QKVSPLIT) {
    const int which = col0 >> 10;
    Cb = (which == 0) ? C0 : (which == 1) ? C1 : C2;
    cbase = col0 & 1023;
  }
  const int NW = QKVSPLIT ? 1024 : N;
#pragma unroll
  for (int m = 0; m < MF; m++) {
#pragma unroll
    for (int n = 0; n < 4; n++) {
#pragma unroll
      for (int i = 0; i < 4; i++) {
        const int r = row0 + wm * (BM / 2) + m * 16 + fg * 4 + i;
        const int c = cbase + wn * 64 + n * 16 + fr;
        float v = acc[m][n][i];
        if (BIAS) v += bias[col0 - cbase + c];
        if (RELU) v = fmaxf(v, 0.f);
        if (RES)  v += res[(size_t)r * NW + c];
        if (OUT_BF16) ((ushort*)Cb)[(size_t)r * NW + c] = f2bf(v);
        else          ((float*)Cb)[(size_t)r * NW + c] = v;
      }
    }
  }
}

// GEMM v6: fine ring (round-11 proven sync), 4-slot BK=32 ring, BN=256,
// 8 waves (2M x 4N). ONE barrier-pair per subtile (16 or 32 MFMA between).
// Chunked bijective XCD swizzle (contiguous lid chunk per XCD -> B panels
// L2-resident). Pointer-increment staging; 4x-unrolled ring (slots static).
// Epilogue: LDS-packed full-line stores.
template <int BM, int NSPLIT, int OUT_BF16, int RELU, int BIAS, int RES, int QKVSPLIT>
__global__ __launch_bounds__(512, 2) void gemm8_kernel(
    const ushort* __restrict__ A, const ushort* __restrict__ Bt,
    const float* __restrict__ bias, const float* __restrict__ res,
    void* __restrict__ C0, void* __restrict__ C1, void* __restrict__ C2,
    int M, int N, int K) {
  constexpr int WR = BM / 2;             // wave rows (128 / 64)
  constexpr int FI = WR / 16;            // A frags per wave (8 / 4)
  constexpr int APASS = BM / 128;        // A gload passes (2 / 1)
  constexpr int LPS = APASS + 2;         // loads/thread per subtile (4 / 3)
  constexpr int SLOT = (BM + 256) * 32;  // ushorts per ring slot
  __shared__ __align__(16) ushort lds[4 * SLOT];

  const int tid = threadIdx.x;
  const int lane = tid & 63, w = tid >> 6;
  const int wm = w >> 2, wn = w & 3;
  const int fr = lane & 15, fg = lane >> 4;

  // chunked bijective XCD swizzle: XCD (lid%8) gets contiguous wg chunk
  const int GX = gridDim.x;
  const int nwg = GX * gridDim.y;
  const int lid = blockIdx.y * GX + blockIdx.x;
  const int wg = (lid & 7) * (nwg >> 3) + (lid >> 3);
  const int row0 = (wg % GX) * BM, col0 = (wg / GX) * 256;

  const int kbeg = (NSPLIT > 1) ? blockIdx.z * (K / NSPLIT) : 0;
  const int nt = (K / NSPLIT) / 32;

  const int scc = tid & 3;   // staging chunk col
  const int sr0 = tid >> 2;  // staging row within a 128-row pass
  const int jswz = (scc ^ ((sr0 >> 1) & 3)) * 8;  // (i*128)>>1 % 4 == 0

  // per-thread global staging pointers, advanced 32 elems per subtile
  const ushort* gA = A + (size_t)(row0 + sr0) * K + kbeg + jswz;
  const ushort* gB = Bt + (size_t)(col0 + sr0) * K + kbeg + jswz;

  f32x4 acc[FI][4] = {};

  auto STAGE = [&](int slot) {
    ushort* ba = lds + slot * SLOT;
#pragma unroll
    for (int i = 0; i < APASS; ++i)
      gload16(gA + (size_t)(i * 128) * K, ba + (i * 512 + w * 64) * 8);
    ushort* bb = ba + BM * 32;
#pragma unroll
    for (int i = 0; i < 2; ++i)
      gload16(gB + (size_t)(i * 128) * K, bb + (i * 512 + w * 64) * 8);
    gA += 32; gB += 32;
  };

  // prologue: 3 subtiles in flight; own slot-0 loads landed; rendezvous
  STAGE(0); STAGE(1); STAGE(2);
  vwait<2 * LPS>();
  __builtin_amdgcn_sched_barrier(0);
  __builtin_amdgcn_s_barrier();
  __builtin_amdgcn_sched_barrier(0);

  for (int sb = 0; sb < nt; sb += 4) {
#pragma unroll
    for (int u = 0; u < 4; ++u) {
      const int s = sb + u;
      const ushort* sa = lds + u * SLOT;          // u == s&3
      const ushort* sbp = sa + BM * 32;
      s16x8 af[4], bf[4];
#pragma unroll
      for (int ni = 0; ni < 4; ++ni) {
        const int rb = wn * 64 + ni * 16 + fr;
        bf[ni] = *(const s16x8*)&sbp[rb * 32 + (fg ^ ((rb >> 1) & 3)) * 8];
      }
#pragma unroll
      for (int mi = 0; mi < 4; ++mi) {
        const int ra = wm * WR + mi * 16 + fr;
        af[mi] = *(const s16x8*)&sa[ra * 32 + (fg ^ ((ra >> 1) & 3)) * 8];
      }
      if (s + 3 < nt) STAGE((u + 3) & 3);
      __builtin_amdgcn_sched_barrier(0);
      __builtin_amdgcn_s_barrier();               // slot u fully landed (all waves)
      __builtin_amdgcn_sched_barrier(0);
      __builtin_amdgcn_s_setprio(1);
#pragma unroll
      for (int mi = 0; mi < 4; ++mi)
#pragma unroll
        for (int ni = 0; ni < 4; ++ni)
          acc[mi][ni] = __builtin_amdgcn_mfma_f32_16x16x32_bf16(
              af[mi], bf[ni], acc[mi][ni], 0, 0, 0);
      __builtin_amdgcn_s_setprio(0);
      if constexpr (FI == 8) {                    // second 64-row half
#pragma unroll
        for (int mi = 0; mi < 4; ++mi) {
          const int ra = wm * WR + 64 + mi * 16 + fr;
          af[mi] = *(const s16x8*)&sa[ra * 32 + (fg ^ ((ra >> 1) & 3)) * 8];
        }
        __builtin_amdgcn_s_setprio(1);
#pragma unroll
        for (int mi = 0; mi < 4; ++mi)
#pragma unroll
          for (int ni = 0; ni < 4; ++ni)
            acc[4 + mi][ni] = __builtin_amdgcn_mfma_f32_16x16x32_bf16(
                af[mi], bf[ni], acc[4 + mi][ni], 0, 0, 0);
        __builtin_amdgcn_s_setprio(0);
      }
      __builtin_amdgcn_sched_barrier(0);
      {  // gate: subtile s+1's loads landed BEFORE the collective barrier
        const int rem = nt - 2 - s;
        if (rem >= 2) vwait<2 * LPS>();
        else if (rem == 1) vwait<LPS>();
        else if (rem == 0) vwait<0>();
      }
      __builtin_amdgcn_s_barrier();
      __builtin_amdgcn_sched_barrier(0);
    }
  }

  // ---- epilogue: LDS-pack wave tile, then 128B-line coalesced stores ----
  // C/D layout: col = lane&15, row = (lane>>4)*4 + reg
  __syncthreads();  // all ring-slot reads complete before repurposing LDS
  ushort* wst = lds + w * (WR * 64);  // wave-private region
#pragma unroll
  for (int mi = 0; mi < FI; ++mi) {
#pragma unroll
    for (int ni = 0; ni < 4; ++ni) {
#pragma unroll
      for (int i = 0; i < 4; ++i) {
        float v = acc[mi][ni][i];
        if (NSPLIT == 1) {
          if (BIAS) v += bias[col0 + wn * 64 + ni * 16 + fr];
          if (RELU) v = fmaxf(v, 0.f);
        }
        wst[(mi * 16 + fg * 4 + i) * 64 + ni * 16 + fr] = f2bf(v);
      }
    }
  }
  const int rr = lane >> 3, cc = (lane & 7) * 8;
  if constexpr (NSPLIT > 1) {
    ushort* P = (ushort*)C0 + (size_t)blockIdx.z * M * N;  // bf16 partials
#pragma unroll
    for (int it = 0; it < WR / 8; ++it) {
      const int r = it * 8 + rr;
      *(uint4*)&P[(size_t)(row0 + wm * WR + r) * N + col0 + wn * 64 + cc] =
          *(const uint4*)&wst[r * 64 + cc];
    }
  } else {
    void* Cb = C0;
    int cbase = col0;
    if (QKVSPLIT) {
      const int which = col0 >> 10;
      Cb = (which == 0) ? C0 : (which == 1) ? C1 : C2;
      cbase = col0 & 1023;
    }
    const int NW = QKVSPLIT ? 1024 : N;
#pragma unroll
    for (int it = 0; it < WR / 8; ++it) {
      const int r = it * 8 + rr;
      *(uint4*)&((ushort*)Cb)[(size_t)(row0 + wm * WR + r) * NW + cbase + wn * 64 + cc] =
          *(const uint4*)&wst[r * 64 + cc];
    }
  }
}

// out = p0 + p1 (bf16 partials) + bias[col] + res (fp32), N=1024
__global__ __launch_bounds__(256) void sum2b_kernel(const ushort* __restrict__ p,
                                                    const float* __restrict__ bias,
                                                    const float* __restrict__ res,
                                                    float* __restrict__ out) {
  const size_t i = ((size_t)blockIdx.x * 256 + threadIdx.x) * 4;
  const size_t MN = (size_t)Mc * Dc;
  const ushort4 a = *(const ushort4*)(p + i);
  const ushort4 b = *(const ushort4*)(p + MN + i);
  const float4 r = *(const float4*)(res + i);
  const float4 bs = *(const float4*)(bias + (i & 1023));
  float4 o;
  o.x = bf2f(a.x) + bf2f(b.x) + bs.x + r.x;
  o.y = bf2f(a.y) + bf2f(b.y) + bs.y + r.y;
  o.z = bf2f(a.z) + bf2f(b.z) + bs.z + r.z;
  o.w = bf2f(a.w) + bf2f(b.w) + bs.w + r.w;
  *(float4*)(out + i) = o;
}

// Flash attention v3 (causal): 8 waves, QBLK=128, KVBLK=64, split-KV x2.
__global__ __launch_bounds__(512) void fattn3_kernel(const ushort* __restrict__ Q,
                                                     const ushort* __restrict__ K,
                                                     const ushort* __restrict__ V,
                                                     float* __restrict__ pacc,
                                                     float* __restrict__ pl) {
  __shared__ __align__(16) ushort Kl[2][64][72];
  __shared__ __align__(16) ushort Vt[2][64][72];
  __shared__ __align__(16) uint32_t Pu[8][512];

  const int tid = threadIdx.x;
  const int lane = tid & 63, w = tid >> 6;
  const int fr = lane & 15, fg = lane >> 4;

  const int bh   = blockIdx.x & 31;
  const int rest = blockIdx.x >> 5;
  const int qb   = 15 - (rest >> 1);
  const int z    = rest & 1;
  const int h = bh & 15, b = bh >> 4;
  const int q0 = qb * 128;
  const size_t hbase = (size_t)b * Tc * Dc + (size_t)h * HSc;

  s16x8 qf0, qf1;
  {
    const ushort* qp = Q + hbase + (size_t)(q0 + w * 16 + fr) * Dc + fg * 8;
    qf0 = *(const s16x8*)(qp);
    qf1 = *(const s16x8*)(qp + 32);
  }

  const int kkey = tid >> 3, kd8 = (tid & 7) * 8;
  const int vkey = tid & 63, vd8 = (tid >> 6) * 8;

  const int t0 = z * (qb + 1), t1 = (z + 1) * (qb + 1);
  uint4 kreg = *(const uint4*)(K + hbase + (size_t)(t0 * 64 + kkey) * Dc + kd8);
  uint4 vreg = *(const uint4*)(V + hbase + (size_t)(t0 * 64 + vkey) * Dc + vd8);

  f32x4 acc[4] = {};
  float ps = 0.f;
  const float Cs = 0.18033688f;  // log2(e)/8 (folds the 1/sqrt(64) scale)

  for (int kt = t0; kt < t1; kt++) {
    const int cur = (kt - t0) & 1;
    *(uint4*)&Kl[cur][kkey][kd8] = kreg;
    {
      union { uint4 v; ushort u[8]; } t; t.v = vreg;
#pragma unroll
      for (int j = 0; j < 8; j++) Vt[cur][vd8 + j][vkey] = t.u[j];
    }
    if (kt + 1 < t1) {
      kreg = *(const uint4*)(K + hbase + (size_t)((kt + 1) * 64 + kkey) * Dc + kd8);
      vreg = *(const uint4*)(V + hbase + (size_t)((kt + 1) * 64 + vkey) * Dc + vd8);
    }
    __syncthreads();

    const bool skip = (kt * 64 > q0 + w * 16 + 15);
    if (!skip) {
      f32x4 s[4] = {};
      __builtin_amdgcn_s_setprio(1);
#pragma unroll
      for (int kf = 0; kf < 4; kf++) {
        const s16x8 k0 = *(const s16x8*)&Kl[cur][kf * 16 + fr][fg * 8];
        const s16x8 k1 = *(const s16x8*)&Kl[cur][kf * 16 + fr][32 + fg * 8];
        s[kf] = __builtin_amdgcn_mfma_f32_16x16x32_bf16(k0, qf0, s[kf], 0, 0, 0);
        s[kf] = __builtin_amdgcn_mfma_f32_16x16x32_bf16(k1, qf1, s[kf], 0, 0, 0);
      }
      __builtin_amdgcn_s_setprio(0);

      const bool diag = (kt * 64 + 63 > q0 + w * 16);
      const int qg = q0 + w * 16 + fr;
#pragma unroll
      for (int kf = 0; kf < 4; kf++) {
        float p[4];
#pragma unroll
        for (int i = 0; i < 4; i++) {
          p[i] = exp2f(s[kf][i] * Cs);
          if (diag) {
            const int kg = kt * 64 + kf * 16 + fg * 4 + i;
            if (kg > qg) p[i] = 0.f;
          }
          ps += p[i];
        }
        uint2 pk;
        pk.x = cvtpk(p[0], p[1]);
        pk.y = cvtpk(p[2], p[3]);
        *(uint2*)&Pu[w][(2 * kf + (fg >> 1)) * 64 + fr * 4 + (fg & 1) * 2] = pk;
      }

      const s16x8 pa0 = *(const s16x8*)&Pu[w][fg * 64 + fr * 4];
      const s16x8 pa1 = *(const s16x8*)&Pu[w][(4 + fg) * 64 + fr * 4];
      __builtin_amdgcn_s_setprio(1);
#pragma unroll
      for (int df = 0; df < 4; df++) {
        const s16x8 v0 = *(const s16x8*)&Vt[cur][df * 16 + fr][fg * 8];
        const s16x8 v1 = *(const s16x8*)&Vt[cur][df * 16 + fr][32 + fg * 8];
        acc[df] = __builtin_amdgcn_mfma_f32_16x16x32_bf16(pa0, v0, acc[df], 0, 0, 0);
        acc[df] = __builtin_amdgcn_mfma_f32_16x16x32_bf16(pa1, v1, acc[df], 0, 0, 0);
      }
      __builtin_amdgcn_s_setprio(0);
    }
  }

  ps += __shfl_xor(ps, 16);
  ps += __shfl_xor(ps, 32);
  if (lane < 16)
    pl[(size_t)z * (32 * 2048) + (size_t)bh * 2048 + q0 + w * 16 + lane] = ps;

  float* pa = pacc + (size_t)z * (32ull * 2048 * 64) + (size_t)bh * 2048 * 64;
#pragma unroll
  for (int i = 0; i < 4; i++) {
    const int qr = q0 + w * 16 + fg * 4 + i;
#pragma unroll
    for (int df = 0; df < 4; df++)
      pa[(size_t)qr * 64 + df * 16 + fr] = acc[df][i];
  }
}

// merge split-KV partials: O[b,t,h*64+d] = bf16((accA+accB)/(lA+lB))
__global__ __launch_bounds__(256) void amerge_kernel(const float* __restrict__ pacc,
                                                     const float* __restrict__ pl,
                                                     ushort* __restrict__ O) {
  const int g = blockIdx.x * 256 + threadIdx.x;
  const int d4 = g & 15;
  const int t  = (g >> 4) & 2047;
  const int bh = g >> 15;
  const int h = bh & 15, b = bh >> 4;
  const size_t base = ((size_t)bh * 2048 + t) * 64 + d4 * 4;
  const float4 a = *(const float4*)(pacc + base);
  const float4 c = *(const float4*)(pacc + 32ull * 2048 * 64 + base);
  const float inv = 1.f / (pl[(size_t)bh * 2048 + t] + pl[32 * 2048 + (size_t)bh * 2048 + t]);
  ushort4 o;
  o.x = f2bf((a.x + c.x) * inv);
  o.y = f2bf((a.y + c.y) * inv);
  o.z = f2bf((a.z + c.z) * inv);
  o.w = f2bf((a.w + c.w) * inv);
  *(ushort4*)&O[((size_t)(b * 2048 + t)) * 1024 + h * 64 + d4 * 4] = o;
}

extern "C" void kernel_launch(void* const* d_in, const int* in_sizes, int n_in,
                              void* d_out, int out_size, void* d_ws, size_t ws_size,
                              hipStream_t stream) {
  const float* x   = (const float*)d_in[0];
  const float* Wq  = (const float*)d_in[1];
  const float* Wk  = (const float*)d_in[2];
  const float* Wv  = (const float*)d_in[3];
  const float* Wo  = (const float*)d_in[4];
  const float* bo  = (const float*)d_in[5];
  const float* W1  = (const float*)d_in[6];
  const float* b1  = (const float*)d_in[7];
  const float* W2  = (const float*)d_in[8];
  const float* b2  = (const float*)d_in[9];
  const float* g1  = (const float*)d_in[10];
  const float* be1 = (const float*)d_in[11];
  const float* g2  = (const float*)d_in[12];
  const float* be2 = (const float*)d_in[13];

  char* ws = (char*)d_ws;
  const size_t MB = 1ull << 20;
  ushort* ln1   = (ushort*)(ws + 0 * MB);   // [M,D] bf16; reused as attn-out
  ushort* qb    = (ushort*)(ws + 8 * MB);   // [M,D] bf16; reused as ln2
  ushort* kb    = (ushort*)(ws + 16 * MB);  // [M,D] bf16
  ushort* vb    = (ushort*)(ws + 24 * MB);  // [M,D] bf16
  ushort* wqkvt = (ushort*)(ws + 32 * MB);  // [3072,1024] bf16
  ushort* wot   = (ushort*)(ws + 38 * MB);  // [1024,1024] bf16
  ushort* w1t   = (ushort*)(ws + 40 * MB);  // [4096,1024] bf16
  ushort* w2t   = (ushort*)(ws + 48 * MB);  // [1024,4096] bf16
  float*  x1    = (float*)(ws + 56 * MB);   // [M,D] f32 (post-attn residual)
  ushort* hb    = (ushort*)(ws + 72 * MB);  // [M,DFF] bf16 (ends at 104 MB)
  float*  pacc  = (float*)(ws + 56 * MB);   // attn partials 2x16MB (56..88)
  float*  plv   = (float*)(ws + 88 * MB);   // attn l partials 2x256KB
  ushort* fpart = (ushort*)(ws + 0 * MB);   // FFN2 bf16 partials: 2x8MB
                                            // (overlays ln1+qb, dead by then)

  tcast_all_kernel<<<12288, 256, 0, stream>>>(Wq, Wk, Wv, Wo, W1, W2,
                                              wqkvt, wot, w1t, w2t);

  ln_kernel<<<Mc, 256, 0, stream>>>(x, g1, be1, ln1);

  // fused QKV projection (ring BM=128): N=3072, split outputs, 384 blocks
  gemm8_kernel<128, 1, 1, 0, 0, 0, 1><<<dim3(32, 12), 512, 0, stream>>>(
      ln1, wqkvt, nullptr, nullptr, qb, kb, vb, Mc, 3072, Dc);

  // flash attention v3: split-KV partials, then linear merge into ln1
  fattn3_kernel<<<1024, 512, 0, stream>>>(qb, kb, vb, pacc, plv);
  amerge_kernel<<<4096, 256, 0, stream>>>(pacc, plv, ln1);

  // output projection + bias + residual(x) -> x1 (fp32)
  gemm3_kernel<64, 1, 0, 0, 1, 1, 0><<<dim3(64, 8), 256, 0, stream>>>(
      ln1, wot, bo, x, x1, nullptr, nullptr, Mc, Dc, Dc);

  ln_kernel<<<Mc, 256, 0, stream>>>(x1, g2, be2, qb);

  // FFN1 (ring BM=256, merged barrier-pair): relu(ln2 @ W1 + b1) -> hb
  gemm8_kernel<256, 1, 1, 1, 1, 0, 0><<<dim3(16, 16), 512, 0, stream>>>(
      qb, w1t, b1, nullptr, hb, nullptr, nullptr, Mc, DFFc, Dc);

  // FFN2 (ring BM=128, split-K x2, bf16 partials), then sum -> d_out
  gemm8_kernel<128, 2, 0, 0, 0, 0, 0><<<dim3(32, 4, 2), 512, 0, stream>>>(
      hb, w2t, nullptr, nullptr, fpart, nullptr, nullptr, Mc, Dc, DFFc);
  sum2b_kernel<<<4096, 256, 0, stream>>>(fpart, b2, x1, (float*)d_out);
}